// Round 3
// baseline (546.503 us; speedup 1.0000x reference)
//
#include <hip/hip_runtime.h>
#include <hip/hip_bf16.h>
#include <stdint.h>

// Problem constants
#define NEXP   16
#define TTOK   32768
#define HIN    2048
#define RNK    128
#define OOUT   2048
#define TE     (TTOK / NEXP)   // 2048 tokens per expert
#define LORA_SCALE 0.25f       // alpha/rank = 32/128

typedef __bf16 bf16_t;
typedef bf16_t bf16x8 __attribute__((ext_vector_type(8)));
typedef float  f32x4  __attribute__((ext_vector_type(4)));

// ---------------------------------------------------------------------------
// Per-expert transpose + fp32->bf16 convert: src f32 [E][Rr][Cc] -> dst bf16 [E][Cc][Rr]
// 32x32 tiles via padded LDS; 256 threads = 32x8.
// ---------------------------------------------------------------------------
__global__ void transpose_cvt_kernel(const float* __restrict__ src,
                                     bf16_t* __restrict__ dst,
                                     int Rr, int Cc)
{
    __shared__ float tile[32][33];
    const int e  = blockIdx.z;
    const int c0 = blockIdx.x * 32;
    const int r0 = blockIdx.y * 32;
    const float* s = src + (size_t)e * Rr * Cc;
    bf16_t*      d = dst + (size_t)e * Rr * Cc;
    const int tx = threadIdx.x & 31;
    const int ty = threadIdx.x >> 5;   // 0..7
#pragma unroll
    for (int j = 0; j < 32; j += 8)
        tile[ty + j][tx] = s[(size_t)(r0 + ty + j) * Cc + (c0 + tx)];
    __syncthreads();
#pragma unroll
    for (int j = 0; j < 32; j += 8)
        d[(size_t)(c0 + ty + j) * Rr + (r0 + tx)] = (bf16_t)tile[tx][ty + j];
}

// ---------------------------------------------------------------------------
// Grouped GEMM:
//   C[m,n] = scale * sum_k A[m,k] * Bt[expert, n, k]
// A:  fp32 [Mtot, K] row-major, rows grouped by expert (TE rows each).
// Bt: bf16 [E][N][K] (n-major, k contiguous -> B-fragment friendly).
// C:  fp32 [Mtot, N].
// 128x128 block tile, BK=32, 256 threads (4 waves, 2x2), wave tile 64x64
// = 4x4 MFMA 16x16x32 tiles. A is converted fp32->bf16 in-register during
// staging; accumulation in fp32 (MFMA C/D).
// ---------------------------------------------------------------------------
__global__ __launch_bounds__(256)
void gemm_grouped_bt(const float* __restrict__ A,
                     const bf16_t* __restrict__ Bt,
                     float* __restrict__ C,
                     int K, int N, float scale)
{
    const int tid  = threadIdx.x;
    const int brow = blockIdx.x;          // 128-row block
    const int bcol = blockIdx.y;          // 128-col block
    const int expert = brow / (TE / 128); // 16 row-blocks per expert
    const int row0 = brow * 128;
    const int col0 = bcol * 128;

    __shared__ bf16_t As[128 * 32];
    __shared__ bf16_t Bs[128 * 32];

    const int wave = tid >> 6;
    const int lane = tid & 63;
    const int wr = (wave >> 1) * 64;      // wave row offset in block tile
    const int wc = (wave & 1) * 64;       // wave col offset
    const int lm = lane & 15;
    const int q  = lane >> 4;

    f32x4 acc[4][4] = {};

    const float*  Ag = A  + (size_t)row0 * K;
    const bf16_t* Bg = Bt + ((size_t)expert * N + col0) * K;

    // staging map: element idx = issue*2048 + tid*8 ; row = idx/32, k = idx%32
    const int sidx0 = tid * 8;
    const int sr0 = sidx0 >> 5, sk0 = sidx0 & 31;
    const int sidx1 = 2048 + tid * 8;
    const int sr1 = sidx1 >> 5, sk1 = sidx1 & 31;

    for (int k0 = 0; k0 < K; k0 += 32) {
        // A: global fp32 -> registers (2x float4 per slot) -> bf16x8
        const float* pa0 = Ag + (size_t)sr0 * K + k0 + sk0;
        const float* pa1 = Ag + (size_t)sr1 * K + k0 + sk1;
        f32x4 a0lo = *(const f32x4*)pa0;
        f32x4 a0hi = *(const f32x4*)(pa0 + 4);
        f32x4 a1lo = *(const f32x4*)pa1;
        f32x4 a1hi = *(const f32x4*)(pa1 + 4);
        // B: global bf16 -> registers (16B per slot)
        bf16x8 b0 = *(const bf16x8*)(Bg + (size_t)sr0 * K + k0 + sk0);
        bf16x8 b1 = *(const bf16x8*)(Bg + (size_t)sr1 * K + k0 + sk1);

        bf16x8 a0, a1;
#pragma unroll
        for (int i = 0; i < 4; ++i) {
            a0[i]     = (bf16_t)a0lo[i];
            a0[4 + i] = (bf16_t)a0hi[i];
            a1[i]     = (bf16_t)a1lo[i];
            a1[4 + i] = (bf16_t)a1hi[i];
        }

        // registers -> LDS (ds_write_b128, conflict-free: tid*16B contiguous)
        *(bf16x8*)(As + sidx0) = a0;
        *(bf16x8*)(As + sidx1) = a1;
        *(bf16x8*)(Bs + sidx0) = b0;
        *(bf16x8*)(Bs + sidx1) = b1;
        __syncthreads();

        bf16x8 af[4], bfr[4];
#pragma unroll
        for (int rt = 0; rt < 4; ++rt)
            af[rt] = *(const bf16x8*)(As + (wr + rt * 16 + lm) * 32 + q * 8);
#pragma unroll
        for (int ct = 0; ct < 4; ++ct)
            bfr[ct] = *(const bf16x8*)(Bs + (wc + ct * 16 + lm) * 32 + q * 8);

#pragma unroll
        for (int rt = 0; rt < 4; ++rt)
#pragma unroll
            for (int ct = 0; ct < 4; ++ct)
                acc[rt][ct] = __builtin_amdgcn_mfma_f32_16x16x32_bf16(
                    af[rt], bfr[ct], acc[rt][ct], 0, 0, 0);

        __syncthreads();   // protects LDS from next iteration's stores
    }

    // epilogue: row = row0+wr+rt*16+q*4+i ; col = col0+wc+ct*16+lm
    // (C/D mapping col=lane&15, row=(lane>>4)*4+reg — m89/m91 verified)
#pragma unroll
    for (int rt = 0; rt < 4; ++rt) {
#pragma unroll
        for (int i = 0; i < 4; ++i) {
            const int grow = row0 + wr + rt * 16 + q * 4 + i;
            float* Crow = C + (size_t)grow * N + col0 + wc;
#pragma unroll
            for (int ct = 0; ct < 4; ++ct)
                Crow[ct * 16 + lm] = acc[rt][ct][i] * scale;
        }
    }
}

// ---------------------------------------------------------------------------
extern "C" void kernel_launch(void* const* d_in, const int* in_sizes, int n_in,
                              void* d_out, int out_size, void* d_ws, size_t ws_size,
                              hipStream_t stream)
{
    const float* x  = (const float*)d_in[0];   // fp32 [TTOK, HIN]
    const float* la = (const float*)d_in[1];   // fp32 [E, HIN, RNK]
    const float* lb = (const float*)d_in[2];   // fp32 [E, RNK, OOUT]
    float* out = (float*)d_out;                // fp32 [TTOK, OOUT]

    // workspace layout:
    //   At  bf16 [E][RNK][HIN]   (8 MB)
    //   Btw bf16 [E][OOUT][RNK]  (8 MB)
    //   low fp32 [TTOK][RNK]     (16 MB)
    bf16_t* At  = (bf16_t*)d_ws;
    bf16_t* Btw = At + (size_t)NEXP * RNK * HIN;
    float*  low = (float*)(Btw + (size_t)NEXP * OOUT * RNK);

    // transpose+convert lora_a: f32 [E][HIN][RNK] -> bf16 At [E][RNK][HIN]
    {
        dim3 g(RNK / 32, HIN / 32, NEXP);
        transpose_cvt_kernel<<<g, 256, 0, stream>>>(la, At, HIN, RNK);
    }
    // transpose+convert lora_b: f32 [E][RNK][OOUT] -> bf16 Btw [E][OOUT][RNK]
    {
        dim3 g(OOUT / 32, RNK / 32, NEXP);
        transpose_cvt_kernel<<<g, 256, 0, stream>>>(lb, Btw, RNK, OOUT);
    }
    // GEMM1: low = x @ A   (M=TTOK grouped, K=HIN, N=RNK)
    {
        dim3 g(TTOK / 128, RNK / 128);
        gemm_grouped_bt<<<g, 256, 0, stream>>>(x, At, low, HIN, RNK, 1.0f);
    }
    // GEMM2: out = (low @ B) * scale   (M=TTOK grouped, K=RNK, N=OOUT)
    {
        dim3 g(TTOK / 128, OOUT / 128);
        gemm_grouped_bt<<<g, 256, 0, stream>>>(low, Btw, out, RNK, OOUT, LORA_SCALE);
    }
}